// Round 10
// baseline (166.996 us; speedup 1.0000x reference)
//
#include <hip/hip_runtime.h>
#include <hip/hip_bf16.h>

// ---------------------------------------------------------------------------
// GraphSAGE 2-layer forward.
//   h   = relu( mean_agg(x) @ W1_l + b1 + x @ W1_r )
//   out =       mean_agg(h) @ W2_l + b2 + h @ W2_r
// agg(x)@W == agg(x@W): transform-then-aggregate. Biases folded into the
// GEMM epilogue of the root term (q = x@W1_r + b1, r = h@W2_r + b2).
// bf16 MFMA GEMMs; bf16 gather buffers (p,g) and addends (q,r); fp32 out.
// CSR build with ZERO global atomics, 128 stripes for latency-parallelism:
//   hist:    8 node-ranges x 128 edge-stripes (6252 edges, 4-aligned);
//            packed 2xushort LDS hist (12.5 KB). Fused into the GEMM-1
//            dispatch with hist blocks FIRST (long pole starts at t=0).
//   scan16:  cnt[n] = sum_j hist, block scan -> row_start.
//   add_off_base: global prefix; absolute cursors (unpacked) to cur.
//   scatter: block (r,j): cursors -> LDS, LDS-atomic position, plain stores
//            into range-r's contiguous csr region (blockIdx&7==r -> XCD-local).
// ---------------------------------------------------------------------------

typedef __attribute__((ext_vector_type(8))) short bf16x8;
typedef __attribute__((ext_vector_type(4))) float f32x4;

static __device__ __forceinline__ float bf_lo(unsigned u) {
    u <<= 16; return __builtin_bit_cast(float, u);
}
static __device__ __forceinline__ float bf_hi(unsigned u) {
    u &= 0xffff0000u; return __builtin_bit_cast(float, u);
}
static __device__ __forceinline__ unsigned short f2bf(float f) {
    __hip_bfloat16 b = __float2bfloat16(f);
    return __builtin_bit_cast(unsigned short, b);
}
static __device__ __forceinline__ unsigned packbf(float lo, float hi) {
    return (unsigned)f2bf(lo) | ((unsigned)f2bf(hi) << 16);
}

#define NRANGE   8
#define RANGE_W  6250      // N == 8*6250 exactly
#define PACKED_W 3125      // RANGE_W/2, two ushort counts per int
#define NSTRIPE  128
#define NHIST    (NRANGE * NSTRIPE)

// stripe length: E/NSTRIPE rounded up to a multiple of 4 (int4 alignment;
// s0 and s1 stay multiples of 4 so e<s1 implies e+3<s1 for e%4==0).
static __device__ __forceinline__ int stripe_len(int E) {
    return ((E / NSTRIPE) + 3) & ~3;
}

// ---------------- weight prep ----------------

__global__ __launch_bounds__(256) void wt_all_kernel(const float* __restrict__ W1l,
                                                     const float* __restrict__ W1r,
                                                     const float* __restrict__ W2l,
                                                     const float* __restrict__ W2r,
                                                     unsigned short* __restrict__ T1l,
                                                     unsigned short* __restrict__ T1r,
                                                     unsigned short* __restrict__ T2l,
                                                     unsigned short* __restrict__ T2r) {
    int i = blockIdx.x * 256 + threadIdx.x;
    if (i < 16384) {
        int k = i >> 7, n = i & 127;
        T1l[n * 128 + k] = f2bf(W1l[i]);
        T1r[n * 128 + k] = f2bf(W1r[i]);
    } else if (i < 16384 + 8192) {
        int m = i - 16384;
        int k = m >> 6, n = m & 63;
        T2l[n * 128 + k] = f2bf(W2l[m]);
        T2r[n * 128 + k] = f2bf(W2r[m]);
    }
}

// ---------------- MFMA dual GEMM body ----------------
// A[M][128] row-major (fp32 if A_F32 else bf16); WTl/WTr[NC][128] bf16 (=W^T).
// Pl = A@Wl (bf16), Qr = A@Wr + bias (bf16). One wave = 16 output rows.
// mfma_f32_16x16x32_bf16: A lane l -> row l&15, k=(l>>4)*8+j; B lane l ->
// col l&15, same k; D: col=lane&15, row=(lane>>4)*4+reg.

template <int NC, bool A_F32>
static __device__ __forceinline__ void gemm_body(
    int bid, int tid, const void* __restrict__ Av,
    const unsigned short* __restrict__ WTl,
    const unsigned short* __restrict__ WTr,
    const float* __restrict__ bias,
    unsigned short* __restrict__ Pl,
    unsigned short* __restrict__ Qr, int M) {
    const int wave = tid >> 6;
    const int lane = tid & 63;
    const int m0 = bid * 64 + wave * 16;
    const int lr = lane & 15;
    const int lk = lane >> 4;

    int arow = m0 + lr;
    if (arow >= M) arow = M - 1;

    bf16x8 af[4];
    if (A_F32) {
        const float* Ab = (const float*)Av + (size_t)arow * 128 + lk * 8;
#pragma unroll
        for (int s = 0; s < 4; ++s) {
            float4 v0 = *(const float4*)(Ab + s * 32);
            float4 v1 = *(const float4*)(Ab + s * 32 + 4);
            unsigned short t[8] = {f2bf(v0.x), f2bf(v0.y), f2bf(v0.z), f2bf(v0.w),
                                   f2bf(v1.x), f2bf(v1.y), f2bf(v1.z), f2bf(v1.w)};
            af[s] = *(const bf16x8*)t;
        }
    } else {
        const unsigned short* Ab = (const unsigned short*)Av + (size_t)arow * 128 + lk * 8;
#pragma unroll
        for (int s = 0; s < 4; ++s) af[s] = *(const bf16x8*)(Ab + s * 32);
    }

#pragma unroll
    for (int ct = 0; ct < NC / 16; ++ct) {
        const unsigned short* Bl = WTl + (size_t)(ct * 16 + lr) * 128 + lk * 8;
        const unsigned short* Br = WTr + (size_t)(ct * 16 + lr) * 128 + lk * 8;
        f32x4 accL = {0.f, 0.f, 0.f, 0.f};
        f32x4 accR = {0.f, 0.f, 0.f, 0.f};
#pragma unroll
        for (int s = 0; s < 4; ++s) {
            bf16x8 bl = *(const bf16x8*)(Bl + s * 32);
            bf16x8 br = *(const bf16x8*)(Br + s * 32);
            accL = __builtin_amdgcn_mfma_f32_16x16x32_bf16(af[s], bl, accL, 0, 0, 0);
            accR = __builtin_amdgcn_mfma_f32_16x16x32_bf16(af[s], br, accR, 0, 0, 0);
        }
        float bcol = bias[ct * 16 + lr];
#pragma unroll
        for (int r = 0; r < 4; ++r) {
            int gr = m0 + lk * 4 + r;
            if (gr < M) {
                Pl[(size_t)gr * NC + ct * 16 + lr] = f2bf(accL[r]);
                Qr[(size_t)gr * NC + ct * 16 + lr] = f2bf(accR[r] + bcol);
            }
        }
    }
}

// ---------------- fused hist + GEMM-1 ----------------
// Blocks [0, NHIST): packed LDS histogram of dst for (range, stripe).
// Blocks [NHIST, +nGemmWg): p = x@W1_l, q = x@W1_r + b1 (fp32 A, fused cvt).
// Hist blocks first: they are the long pole; GEMM blocks backfill.

__global__ __launch_bounds__(256) void gemm1_hist_kernel(
    const float* __restrict__ x,
    const unsigned short* __restrict__ wt1l,
    const unsigned short* __restrict__ wt1r,
    const float* __restrict__ b1,
    unsigned short* __restrict__ Pl,
    unsigned short* __restrict__ Qr, int M,
    const int* __restrict__ dst, int* __restrict__ hist,
    int E, int N) {
    __shared__ int lhist[PACKED_W];
    const int tid = threadIdx.x;
    if ((int)blockIdx.x >= NHIST) {
        gemm_body<128, true>(blockIdx.x - NHIST, tid, x, wt1l, wt1r, b1, Pl, Qr, M);
        return;
    }
    const int b = blockIdx.x;
    const int r = b & (NRANGE - 1);
    const int j = b >> 3;
    const int lo = r * RANGE_W;
    const int w = min(N - lo, RANGE_W);
    for (int i = tid; i < PACKED_W; i += 256) lhist[i] = 0;
    __syncthreads();
    const int stripe = stripe_len(E);
    const int s0 = j * stripe;
    const int s1 = min(E, s0 + stripe);
    for (int e = s0 + tid * 4; e < s1; e += 1024) {
        int4 d4 = *(const int4*)(dst + e);
        int a0 = d4.x - lo, a1 = d4.y - lo, a2 = d4.z - lo, a3 = d4.w - lo;
        if ((unsigned)a0 < (unsigned)w) atomicAdd(&lhist[a0 >> 1], 1u << ((a0 & 1) * 16));
        if ((unsigned)a1 < (unsigned)w) atomicAdd(&lhist[a1 >> 1], 1u << ((a1 & 1) * 16));
        if ((unsigned)a2 < (unsigned)w) atomicAdd(&lhist[a2 >> 1], 1u << ((a2 & 1) * 16));
        if ((unsigned)a3 < (unsigned)w) atomicAdd(&lhist[a3 >> 1], 1u << ((a3 & 1) * 16));
    }
    __syncthreads();
    int* gh = hist + ((size_t)r * NSTRIPE + j) * PACKED_W;
    for (int i = tid; i < PACKED_W; i += 256) gh[i] = lhist[i];
}

// ---------------- CSR scan ----------------

__global__ __launch_bounds__(256) void scan16_kernel(const int* __restrict__ hist,
                                                     int* __restrict__ row_start,
                                                     int* __restrict__ bsum, int N) {
    __shared__ int lds[256];
    int i = blockIdx.x * 256 + threadIdx.x;
    int v = 0;
    if (i < N) {
        int r = i / RANGE_W, loc = i - r * RANGE_W;
        const int* hp = hist + (size_t)r * NSTRIPE * PACKED_W + (loc >> 1);
        int sh = (loc & 1) * 16;
#pragma unroll 8
        for (int j = 0; j < NSTRIPE; ++j) v += (hp[j * PACKED_W] >> sh) & 0xffff;
    }
    lds[threadIdx.x] = v;
    __syncthreads();
    for (int off = 1; off < 256; off <<= 1) {
        int t = (threadIdx.x >= off) ? lds[threadIdx.x - off] : 0;
        __syncthreads();
        lds[threadIdx.x] += t;
        __syncthreads();
    }
    if (i < N) row_start[i] = lds[threadIdx.x] - v;
    if (threadIdx.x == 255) bsum[blockIdx.x] = lds[255];
}

// global prefix via bsum reduce; row_start finalized; absolute per-
// (range,stripe,node) cursors written UNPACKED to cur.
__global__ __launch_bounds__(256) void add_off_base_kernel(int* __restrict__ row_start,
                                                           const int* __restrict__ bsum,
                                                           const int* __restrict__ hist,
                                                           int* __restrict__ cur,
                                                           int N, int E) {
    __shared__ int lds[256];
    int b = blockIdx.x;
    lds[threadIdx.x] = (threadIdx.x < b) ? bsum[threadIdx.x] : 0;
    __syncthreads();
    for (int off = 128; off > 0; off >>= 1) {
        if (threadIdx.x < off) lds[threadIdx.x] += lds[threadIdx.x + off];
        __syncthreads();
    }
    int prefix = lds[0];
    int i = b * 256 + threadIdx.x;
    if (i < N) {
        int s = row_start[i] + prefix;
        row_start[i] = s;
        int r = i / RANGE_W, loc = i - r * RANGE_W;
        const int* hp = hist + (size_t)r * NSTRIPE * PACKED_W + (loc >> 1);
        int* cp = cur + (size_t)r * NSTRIPE * RANGE_W + loc;
        int sh = (loc & 1) * 16;
#pragma unroll 4
        for (int j = 0; j < NSTRIPE; ++j) {
            int h = (hp[j * PACKED_W] >> sh) & 0xffff;
            cp[j * RANGE_W] = s;
            s += h;
        }
    }
    if (b == 0 && threadIdx.x == 0) row_start[N] = E;
}

// ---------------- scatter (LDS cursors, no global atomics) ----------------

__global__ __launch_bounds__(256) void scatter_lds_kernel(const int* __restrict__ src,
                                                          const int* __restrict__ dst,
                                                          const int* __restrict__ cur,
                                                          int* __restrict__ csr_src,
                                                          int E, int N) {
    __shared__ int lcur[RANGE_W];
    const int tid = threadIdx.x;
    const int b = blockIdx.x;
    const int r = b & (NRANGE - 1);
    const int j = b >> 3;
    const int lo = r * RANGE_W;
    const int w = min(N - lo, RANGE_W);
    const int* gb = cur + ((size_t)r * NSTRIPE + j) * RANGE_W;
    for (int i = tid; i < w; i += 256) lcur[i] = gb[i];
    __syncthreads();
    const int stripe = stripe_len(E);
    const int s0 = j * stripe;
    const int s1 = min(E, s0 + stripe);
    for (int e = s0 + tid * 4; e < s1; e += 1024) {
        int4 d4 = *(const int4*)(dst + e);
        int4 v4 = *(const int4*)(src + e);
        int a0 = d4.x - lo, a1 = d4.y - lo, a2 = d4.z - lo, a3 = d4.w - lo;
        if ((unsigned)a0 < (unsigned)w) { int p = atomicAdd(&lcur[a0], 1); csr_src[p] = v4.x; }
        if ((unsigned)a1 < (unsigned)w) { int p = atomicAdd(&lcur[a1], 1); csr_src[p] = v4.y; }
        if ((unsigned)a2 < (unsigned)w) { int p = atomicAdd(&lcur[a2], 1); csr_src[p] = v4.z; }
        if ((unsigned)a3 < (unsigned)w) { int p = atomicAdd(&lcur[a3], 1); csr_src[p] = v4.w; }
    }
}

__global__ __launch_bounds__(256) void mfma_dual_gemm2(
    const unsigned short* __restrict__ A,
    const unsigned short* __restrict__ WTl,
    const unsigned short* __restrict__ WTr,
    const float* __restrict__ b2,
    unsigned short* __restrict__ Pl,
    unsigned short* __restrict__ Qr, int M) {
    gemm_body<64, false>(blockIdx.x, threadIdx.x, A, WTl, WTr, b2, Pl, Qr, M);
}

// ---------------- aggregation ----------------
// layer 1: h[n] = relu( mean(p[src]) + q[n] ); p,q,h bf16; 128 ch.
// 16 nodes/block; 4 nodes per wave, 16 lanes/node, 8 ch (16B) per lane.
__global__ __launch_bounds__(256) void agg1_kernel(const unsigned short* __restrict__ p,
                                                   const unsigned short* __restrict__ q,
                                                   const int* __restrict__ row_start,
                                                   const int* __restrict__ csr_src,
                                                   unsigned short* __restrict__ h, int N) {
    int tid = threadIdx.x;
    int n = blockIdx.x * 16 + (tid >> 4);
    int lane = tid & 15;
    if (n >= N) return;
    int s0 = row_start[n], s1 = row_start[n + 1];
    float acc[8] = {};
    const unsigned short* pc = p + lane * 8;
    int e = s0;
    for (; e + 3 < s1; e += 4) {
        uint4 v0 = *(const uint4*)(pc + (size_t)csr_src[e]     * 128);
        uint4 v1 = *(const uint4*)(pc + (size_t)csr_src[e + 1] * 128);
        uint4 v2 = *(const uint4*)(pc + (size_t)csr_src[e + 2] * 128);
        uint4 v3 = *(const uint4*)(pc + (size_t)csr_src[e + 3] * 128);
        acc[0] += (bf_lo(v0.x) + bf_lo(v1.x)) + (bf_lo(v2.x) + bf_lo(v3.x));
        acc[1] += (bf_hi(v0.x) + bf_hi(v1.x)) + (bf_hi(v2.x) + bf_hi(v3.x));
        acc[2] += (bf_lo(v0.y) + bf_lo(v1.y)) + (bf_lo(v2.y) + bf_lo(v3.y));
        acc[3] += (bf_hi(v0.y) + bf_hi(v1.y)) + (bf_hi(v2.y) + bf_hi(v3.y));
        acc[4] += (bf_lo(v0.z) + bf_lo(v1.z)) + (bf_lo(v2.z) + bf_lo(v3.z));
        acc[5] += (bf_hi(v0.z) + bf_hi(v1.z)) + (bf_hi(v2.z) + bf_hi(v3.z));
        acc[6] += (bf_lo(v0.w) + bf_lo(v1.w)) + (bf_lo(v2.w) + bf_lo(v3.w));
        acc[7] += (bf_hi(v0.w) + bf_hi(v1.w)) + (bf_hi(v2.w) + bf_hi(v3.w));
    }
    for (; e < s1; ++e) {
        uint4 v0 = *(const uint4*)(pc + (size_t)csr_src[e] * 128);
        acc[0] += bf_lo(v0.x); acc[1] += bf_hi(v0.x);
        acc[2] += bf_lo(v0.y); acc[3] += bf_hi(v0.y);
        acc[4] += bf_lo(v0.z); acc[5] += bf_hi(v0.z);
        acc[6] += bf_lo(v0.w); acc[7] += bf_hi(v0.w);
    }
    float inv = 1.0f / (float)max(s1 - s0, 1);
    uint4 qv = *(const uint4*)(q + (size_t)n * 128 + lane * 8);
    float hv[8];
    hv[0] = fmaxf(fmaf(acc[0], inv, bf_lo(qv.x)), 0.f);
    hv[1] = fmaxf(fmaf(acc[1], inv, bf_hi(qv.x)), 0.f);
    hv[2] = fmaxf(fmaf(acc[2], inv, bf_lo(qv.y)), 0.f);
    hv[3] = fmaxf(fmaf(acc[3], inv, bf_hi(qv.y)), 0.f);
    hv[4] = fmaxf(fmaf(acc[4], inv, bf_lo(qv.z)), 0.f);
    hv[5] = fmaxf(fmaf(acc[5], inv, bf_hi(qv.z)), 0.f);
    hv[6] = fmaxf(fmaf(acc[6], inv, bf_lo(qv.w)), 0.f);
    hv[7] = fmaxf(fmaf(acc[7], inv, bf_hi(qv.w)), 0.f);
    uint4 o;
    o.x = packbf(hv[0], hv[1]); o.y = packbf(hv[2], hv[3]);
    o.z = packbf(hv[4], hv[5]); o.w = packbf(hv[6], hv[7]);
    *(uint4*)(h + (size_t)n * 128 + lane * 8) = o;
}

// layer 2: out[n] = mean(g[src]) + r[n]; g,r bf16; out f32; 64 ch.
__global__ __launch_bounds__(256) void agg2_kernel(const unsigned short* __restrict__ g,
                                                   const unsigned short* __restrict__ r,
                                                   const int* __restrict__ row_start,
                                                   const int* __restrict__ csr_src,
                                                   float* __restrict__ out, int N) {
    int tid = threadIdx.x;
    int n = blockIdx.x * 16 + (tid >> 4);
    int lane = tid & 15;
    if (n >= N) return;
    int s0 = row_start[n], s1 = row_start[n + 1];
    float acc[4] = {};
    const unsigned short* gc = g + lane * 4;
    int e = s0;
    for (; e + 3 < s1; e += 4) {
        uint2 v0 = *(const uint2*)(gc + (size_t)csr_src[e]     * 64);
        uint2 v1 = *(const uint2*)(gc + (size_t)csr_src[e + 1] * 64);
        uint2 v2 = *(const uint2*)(gc + (size_t)csr_src[e + 2] * 64);
        uint2 v3 = *(const uint2*)(gc + (size_t)csr_src[e + 3] * 64);
        acc[0] += (bf_lo(v0.x) + bf_lo(v1.x)) + (bf_lo(v2.x) + bf_lo(v3.x));
        acc[1] += (bf_hi(v0.x) + bf_hi(v1.x)) + (bf_hi(v2.x) + bf_hi(v3.x));
        acc[2] += (bf_lo(v0.y) + bf_lo(v1.y)) + (bf_lo(v2.y) + bf_lo(v3.y));
        acc[3] += (bf_hi(v0.y) + bf_hi(v1.y)) + (bf_hi(v2.y) + bf_hi(v3.y));
    }
    for (; e < s1; ++e) {
        uint2 v0 = *(const uint2*)(gc + (size_t)csr_src[e] * 64);
        acc[0] += bf_lo(v0.x); acc[1] += bf_hi(v0.x);
        acc[2] += bf_lo(v0.y); acc[3] += bf_hi(v0.y);
    }
    float inv = 1.0f / (float)max(s1 - s0, 1);
    uint2 rv = *(const uint2*)(r + (size_t)n * 64 + lane * 4);
    float4 o;
    o.x = fmaf(acc[0], inv, bf_lo(rv.x));
    o.y = fmaf(acc[1], inv, bf_hi(rv.x));
    o.z = fmaf(acc[2], inv, bf_lo(rv.y));
    o.w = fmaf(acc[3], inv, bf_hi(rv.y));
    *(float4*)(out + (size_t)n * 64 + lane * 4) = o;
}

// ---------------------------------------------------------------------------

extern "C" void kernel_launch(void* const* d_in, const int* in_sizes, int n_in,
                              void* d_out, int out_size, void* d_ws, size_t ws_size,
                              hipStream_t stream) {
    const float* x    = (const float*)d_in[0];
    const int*   ei   = (const int*)d_in[1];
    const float* W1_l = (const float*)d_in[2];
    const float* b1   = (const float*)d_in[3];
    const float* W1_r = (const float*)d_in[4];
    const float* W2_l = (const float*)d_in[5];
    const float* b2   = (const float*)d_in[6];
    const float* W2_r = (const float*)d_in[7];

    const int N = in_sizes[0] / 128;   // 50000
    const int E = in_sizes[1] / 2;     // 800000
    const int* e_src = ei;
    const int* e_dst = ei + E;

    // ---- workspace layout ----
    char* ws = (char*)d_ws;
    auto align256 = [](size_t v) { return (v + 255) & ~(size_t)255; };
    size_t off = 0;
    int* row_start = (int*)(ws + off); off += align256((size_t)(N + 1) * 4);
    int* bsum      = (int*)(ws + off); off += align256(1024);
    int* hist      = (int*)(ws + off); off += align256((size_t)NRANGE * NSTRIPE * PACKED_W * 4);
    int* cur       = (int*)(ws + off); off += align256((size_t)NRANGE * NSTRIPE * RANGE_W * 4);
    int* csr_src   = (int*)(ws + off); off += align256((size_t)E * 4);
    unsigned short* h_bf  = (unsigned short*)(ws + off); off += align256((size_t)N * 128 * 2);
    unsigned short* pg_bf = (unsigned short*)(ws + off); off += align256((size_t)N * 128 * 2);
    unsigned short* qr_bf = (unsigned short*)(ws + off); off += align256((size_t)N * 128 * 2);
    unsigned short* wt1l  = (unsigned short*)(ws + off); off += align256(128 * 128 * 2);
    unsigned short* wt1r  = (unsigned short*)(ws + off); off += align256(128 * 128 * 2);
    unsigned short* wt2l  = (unsigned short*)(ws + off); off += align256(128 * 64 * 2);
    unsigned short* wt2r  = (unsigned short*)(ws + off); off += align256(128 * 64 * 2);
    float* out = (float*)d_out;

    const int nb = (N + 255) / 256;
    const int nGemmWg = (N + 63) / 64;

    // ---- weight prep ----
    wt_all_kernel<<<(16384 + 8192 + 255) / 256, 256, 0, stream>>>(
        W1_l, W1_r, W2_l, W2_r, wt1l, wt1r, wt2l, wt2r);
    // ---- histogram (blocks 0..NHIST) overlapped with GEMM-1 (p, q+b1) ----
    gemm1_hist_kernel<<<NHIST + nGemmWg, 256, 0, stream>>>(
        x, wt1l, wt1r, b1, pg_bf, qr_bf, N, e_dst, hist, E, N);
    // ---- CSR finish (no global atomics) ----
    scan16_kernel<<<nb, 256, 0, stream>>>(hist, row_start, bsum, N);
    add_off_base_kernel<<<nb, 256, 0, stream>>>(row_start, bsum, hist, cur, N, E);
    scatter_lds_kernel<<<NHIST, 256, 0, stream>>>(e_src, e_dst, cur,
                                                  csr_src, E, N);
    // ---- layer 1 aggregate ----
    agg1_kernel<<<(N + 15) / 16, 256, 0, stream>>>(pg_bf, qr_bf, row_start,
                                                   csr_src, h_bf, N);
    // ---- layer 2 ----
    mfma_dual_gemm2<<<(N + 63) / 64, 256, 0, stream>>>(h_bf, wt2l, wt2r, b2,
                                                       pg_bf, qr_bf, N);
    agg2_kernel<<<(N + 15) / 16, 256, 0, stream>>>(pg_bf, qr_bf, row_start,
                                                   csr_src, out, N);
}

// Round 11
// 147.729 us; speedup vs baseline: 1.1304x; 1.1304x over previous
//
#include <hip/hip_runtime.h>
#include <hip/hip_bf16.h>

// ---------------------------------------------------------------------------
// GraphSAGE 2-layer forward.
//   h   = relu( mean_agg(x) @ W1_l + b1 + x @ W1_r )
//   out =       mean_agg(h) @ W2_l + b2 + h @ W2_r
// agg(x)@W == agg(x@W): transform-then-aggregate. Biases folded into the
// GEMM epilogue of the root term (q = x@W1_r + b1, r = h@W2_r + b2).
// bf16 MFMA GEMMs; bf16 gather buffers (p,g) and addends (q,r); fp32 out.
// CSR build with ZERO global atomics (NSTRIPE=32; 128 regressed r10):
//   D1 hist+wt: 8 ranges x 32 stripes packed 2xushort LDS hist (12.5 KB),
//               hist blocks first, weight-transpose blocks backfill.
//   D2 scan16:  cnt[n] = sum_j hist, block scan -> row_start.
//   D3 add_off_base: global prefix; absolute cursors (unpacked) to cur.
//   D4 scatter+GEMM1: scatter blocks first (cursors->LDS, LDS-atomic pos,
//               plain stores, blockIdx&7==range -> XCD-local); GEMM-1
//               blocks backfill (p,q only needed later by agg1).
// ---------------------------------------------------------------------------

typedef __attribute__((ext_vector_type(8))) short bf16x8;
typedef __attribute__((ext_vector_type(4))) float f32x4;

static __device__ __forceinline__ float bf_lo(unsigned u) {
    u <<= 16; return __builtin_bit_cast(float, u);
}
static __device__ __forceinline__ float bf_hi(unsigned u) {
    u &= 0xffff0000u; return __builtin_bit_cast(float, u);
}
static __device__ __forceinline__ unsigned short f2bf(float f) {
    __hip_bfloat16 b = __float2bfloat16(f);
    return __builtin_bit_cast(unsigned short, b);
}
static __device__ __forceinline__ unsigned packbf(float lo, float hi) {
    return (unsigned)f2bf(lo) | ((unsigned)f2bf(hi) << 16);
}

#define NRANGE   8
#define RANGE_W  6250      // N == 8*6250 exactly
#define PACKED_W 3125      // RANGE_W/2, two ushort counts per int
#define NSTRIPE  32
#define NHIST    (NRANGE * NSTRIPE)   // 256

static __device__ __forceinline__ int stripe_len(int E) {
    return ((E / NSTRIPE) + 3) & ~3;  // multiple of 4 for int4 alignment
}

// ---------------- MFMA dual GEMM body ----------------
// A[M][128] row-major (fp32 if A_F32 else bf16); WTl/WTr[NC][128] bf16 (=W^T).
// Pl = A@Wl (bf16), Qr = A@Wr + bias (bf16). One wave = 16 output rows.
// mfma_f32_16x16x32_bf16: A lane l -> row l&15, k=(l>>4)*8+j; B lane l ->
// col l&15, same k; D: col=lane&15, row=(lane>>4)*4+reg.

template <int NC, bool A_F32>
static __device__ __forceinline__ void gemm_body(
    int bid, int tid, const void* __restrict__ Av,
    const unsigned short* __restrict__ WTl,
    const unsigned short* __restrict__ WTr,
    const float* __restrict__ bias,
    unsigned short* __restrict__ Pl,
    unsigned short* __restrict__ Qr, int M) {
    const int wave = tid >> 6;
    const int lane = tid & 63;
    const int m0 = bid * 64 + wave * 16;
    const int lr = lane & 15;
    const int lk = lane >> 4;

    int arow = m0 + lr;
    if (arow >= M) arow = M - 1;

    bf16x8 af[4];
    if (A_F32) {
        const float* Ab = (const float*)Av + (size_t)arow * 128 + lk * 8;
#pragma unroll
        for (int s = 0; s < 4; ++s) {
            float4 v0 = *(const float4*)(Ab + s * 32);
            float4 v1 = *(const float4*)(Ab + s * 32 + 4);
            unsigned short t[8] = {f2bf(v0.x), f2bf(v0.y), f2bf(v0.z), f2bf(v0.w),
                                   f2bf(v1.x), f2bf(v1.y), f2bf(v1.z), f2bf(v1.w)};
            af[s] = *(const bf16x8*)t;
        }
    } else {
        const unsigned short* Ab = (const unsigned short*)Av + (size_t)arow * 128 + lk * 8;
#pragma unroll
        for (int s = 0; s < 4; ++s) af[s] = *(const bf16x8*)(Ab + s * 32);
    }

#pragma unroll
    for (int ct = 0; ct < NC / 16; ++ct) {
        const unsigned short* Bl = WTl + (size_t)(ct * 16 + lr) * 128 + lk * 8;
        const unsigned short* Br = WTr + (size_t)(ct * 16 + lr) * 128 + lk * 8;
        f32x4 accL = {0.f, 0.f, 0.f, 0.f};
        f32x4 accR = {0.f, 0.f, 0.f, 0.f};
#pragma unroll
        for (int s = 0; s < 4; ++s) {
            bf16x8 bl = *(const bf16x8*)(Bl + s * 32);
            bf16x8 br = *(const bf16x8*)(Br + s * 32);
            accL = __builtin_amdgcn_mfma_f32_16x16x32_bf16(af[s], bl, accL, 0, 0, 0);
            accR = __builtin_amdgcn_mfma_f32_16x16x32_bf16(af[s], br, accR, 0, 0, 0);
        }
        float bcol = bias[ct * 16 + lr];
#pragma unroll
        for (int r = 0; r < 4; ++r) {
            int gr = m0 + lk * 4 + r;
            if (gr < M) {
                Pl[(size_t)gr * NC + ct * 16 + lr] = f2bf(accL[r]);
                Qr[(size_t)gr * NC + ct * 16 + lr] = f2bf(accR[r] + bcol);
            }
        }
    }
}

// ---------------- D1: hist (blocks 0..NHIST) + weight prep (backfill) ------

__global__ __launch_bounds__(256) void hist_wt_kernel(
    const int* __restrict__ dst, int* __restrict__ hist, int E, int N,
    const float* __restrict__ W1l, const float* __restrict__ W1r,
    const float* __restrict__ W2l, const float* __restrict__ W2r,
    unsigned short* __restrict__ T1l, unsigned short* __restrict__ T1r,
    unsigned short* __restrict__ T2l, unsigned short* __restrict__ T2r) {
    __shared__ int lhist[PACKED_W];
    const int tid = threadIdx.x;
    if ((int)blockIdx.x >= NHIST) {
        int i = (blockIdx.x - NHIST) * 256 + tid;
        if (i < 16384) {
            int k = i >> 7, n = i & 127;
            T1l[n * 128 + k] = f2bf(W1l[i]);
            T1r[n * 128 + k] = f2bf(W1r[i]);
        } else if (i < 16384 + 8192) {
            int m = i - 16384;
            int k = m >> 6, n = m & 63;
            T2l[n * 128 + k] = f2bf(W2l[m]);
            T2r[n * 128 + k] = f2bf(W2r[m]);
        }
        return;
    }
    const int b = blockIdx.x;
    const int r = b & (NRANGE - 1);
    const int j = b >> 3;
    const int lo = r * RANGE_W;
    const int w = min(N - lo, RANGE_W);
    for (int i = tid; i < PACKED_W; i += 256) lhist[i] = 0;
    __syncthreads();
    const int stripe = stripe_len(E);
    const int s0 = j * stripe;
    const int s1 = min(E, s0 + stripe);
    for (int e = s0 + tid * 4; e < s1; e += 1024) {
        int4 d4 = *(const int4*)(dst + e);
        int a0 = d4.x - lo, a1 = d4.y - lo, a2 = d4.z - lo, a3 = d4.w - lo;
        if ((unsigned)a0 < (unsigned)w) atomicAdd(&lhist[a0 >> 1], 1u << ((a0 & 1) * 16));
        if ((unsigned)a1 < (unsigned)w) atomicAdd(&lhist[a1 >> 1], 1u << ((a1 & 1) * 16));
        if ((unsigned)a2 < (unsigned)w) atomicAdd(&lhist[a2 >> 1], 1u << ((a2 & 1) * 16));
        if ((unsigned)a3 < (unsigned)w) atomicAdd(&lhist[a3 >> 1], 1u << ((a3 & 1) * 16));
    }
    __syncthreads();
    int* gh = hist + ((size_t)r * NSTRIPE + j) * PACKED_W;
    for (int i = tid; i < PACKED_W; i += 256) gh[i] = lhist[i];
}

// ---------------- D2: scan ----------------

__global__ __launch_bounds__(256) void scan16_kernel(const int* __restrict__ hist,
                                                     int* __restrict__ row_start,
                                                     int* __restrict__ bsum, int N) {
    __shared__ int lds[256];
    int i = blockIdx.x * 256 + threadIdx.x;
    int v = 0;
    if (i < N) {
        int r = i / RANGE_W, loc = i - r * RANGE_W;
        const int* hp = hist + (size_t)r * NSTRIPE * PACKED_W + (loc >> 1);
        int sh = (loc & 1) * 16;
#pragma unroll 8
        for (int j = 0; j < NSTRIPE; ++j) v += (hp[j * PACKED_W] >> sh) & 0xffff;
    }
    lds[threadIdx.x] = v;
    __syncthreads();
    for (int off = 1; off < 256; off <<= 1) {
        int t = (threadIdx.x >= off) ? lds[threadIdx.x - off] : 0;
        __syncthreads();
        lds[threadIdx.x] += t;
        __syncthreads();
    }
    if (i < N) row_start[i] = lds[threadIdx.x] - v;
    if (threadIdx.x == 255) bsum[blockIdx.x] = lds[255];
}

// ---------------- D3: global prefix + absolute cursors ----------------

__global__ __launch_bounds__(256) void add_off_base_kernel(int* __restrict__ row_start,
                                                           const int* __restrict__ bsum,
                                                           const int* __restrict__ hist,
                                                           int* __restrict__ cur,
                                                           int N, int E) {
    __shared__ int lds[256];
    int b = blockIdx.x;
    lds[threadIdx.x] = (threadIdx.x < b) ? bsum[threadIdx.x] : 0;
    __syncthreads();
    for (int off = 128; off > 0; off >>= 1) {
        if (threadIdx.x < off) lds[threadIdx.x] += lds[threadIdx.x + off];
        __syncthreads();
    }
    int prefix = lds[0];
    int i = b * 256 + threadIdx.x;
    if (i < N) {
        int s = row_start[i] + prefix;
        row_start[i] = s;
        int r = i / RANGE_W, loc = i - r * RANGE_W;
        const int* hp = hist + (size_t)r * NSTRIPE * PACKED_W + (loc >> 1);
        int* cp = cur + (size_t)r * NSTRIPE * RANGE_W + loc;
        int sh = (loc & 1) * 16;
#pragma unroll 8
        for (int j = 0; j < NSTRIPE; ++j) {
            int h = (hp[j * PACKED_W] >> sh) & 0xffff;
            cp[j * RANGE_W] = s;
            s += h;
        }
    }
    if (b == 0 && threadIdx.x == 0) row_start[N] = E;
}

// ---------------- D4: scatter (blocks 0..NHIST) + GEMM-1 (backfill) --------

__global__ __launch_bounds__(256) void scatter_gemm1_kernel(
    const int* __restrict__ src, const int* __restrict__ dst,
    const int* __restrict__ cur, int* __restrict__ csr_src, int E, int N,
    const float* __restrict__ x,
    const unsigned short* __restrict__ wt1l,
    const unsigned short* __restrict__ wt1r,
    const float* __restrict__ b1,
    unsigned short* __restrict__ Pl,
    unsigned short* __restrict__ Qr, int M) {
    __shared__ int lcur[RANGE_W];
    const int tid = threadIdx.x;
    if ((int)blockIdx.x >= NHIST) {
        gemm_body<128, true>(blockIdx.x - NHIST, tid, x, wt1l, wt1r, b1, Pl, Qr, M);
        return;
    }
    const int b = blockIdx.x;
    const int r = b & (NRANGE - 1);
    const int j = b >> 3;
    const int lo = r * RANGE_W;
    const int w = min(N - lo, RANGE_W);
    const int* gb = cur + ((size_t)r * NSTRIPE + j) * RANGE_W;
    for (int i = tid; i < w; i += 256) lcur[i] = gb[i];
    __syncthreads();
    const int stripe = stripe_len(E);
    const int s0 = j * stripe;
    const int s1 = min(E, s0 + stripe);
    for (int e = s0 + tid * 4; e < s1; e += 1024) {
        int4 d4 = *(const int4*)(dst + e);
        int4 v4 = *(const int4*)(src + e);
        int a0 = d4.x - lo, a1 = d4.y - lo, a2 = d4.z - lo, a3 = d4.w - lo;
        if ((unsigned)a0 < (unsigned)w) { int p = atomicAdd(&lcur[a0], 1); csr_src[p] = v4.x; }
        if ((unsigned)a1 < (unsigned)w) { int p = atomicAdd(&lcur[a1], 1); csr_src[p] = v4.y; }
        if ((unsigned)a2 < (unsigned)w) { int p = atomicAdd(&lcur[a2], 1); csr_src[p] = v4.z; }
        if ((unsigned)a3 < (unsigned)w) { int p = atomicAdd(&lcur[a3], 1); csr_src[p] = v4.w; }
    }
}

__global__ __launch_bounds__(256) void mfma_dual_gemm2(
    const unsigned short* __restrict__ A,
    const unsigned short* __restrict__ WTl,
    const unsigned short* __restrict__ WTr,
    const float* __restrict__ b2,
    unsigned short* __restrict__ Pl,
    unsigned short* __restrict__ Qr, int M) {
    gemm_body<64, false>(blockIdx.x, threadIdx.x, A, WTl, WTr, b2, Pl, Qr, M);
}

// ---------------- aggregation ----------------
// layer 1: h[n] = relu( mean(p[src]) + q[n] ); p,q,h bf16; 128 ch.
// 16 nodes/block; 4 nodes per wave, 16 lanes/node, 8 ch (16B) per lane.
__global__ __launch_bounds__(256) void agg1_kernel(const unsigned short* __restrict__ p,
                                                   const unsigned short* __restrict__ q,
                                                   const int* __restrict__ row_start,
                                                   const int* __restrict__ csr_src,
                                                   unsigned short* __restrict__ h, int N) {
    int tid = threadIdx.x;
    int n = blockIdx.x * 16 + (tid >> 4);
    int lane = tid & 15;
    if (n >= N) return;
    int s0 = row_start[n], s1 = row_start[n + 1];
    float acc[8] = {};
    const unsigned short* pc = p + lane * 8;
    int e = s0;
    for (; e + 3 < s1; e += 4) {
        uint4 v0 = *(const uint4*)(pc + (size_t)csr_src[e]     * 128);
        uint4 v1 = *(const uint4*)(pc + (size_t)csr_src[e + 1] * 128);
        uint4 v2 = *(const uint4*)(pc + (size_t)csr_src[e + 2] * 128);
        uint4 v3 = *(const uint4*)(pc + (size_t)csr_src[e + 3] * 128);
        acc[0] += (bf_lo(v0.x) + bf_lo(v1.x)) + (bf_lo(v2.x) + bf_lo(v3.x));
        acc[1] += (bf_hi(v0.x) + bf_hi(v1.x)) + (bf_hi(v2.x) + bf_hi(v3.x));
        acc[2] += (bf_lo(v0.y) + bf_lo(v1.y)) + (bf_lo(v2.y) + bf_lo(v3.y));
        acc[3] += (bf_hi(v0.y) + bf_hi(v1.y)) + (bf_hi(v2.y) + bf_hi(v3.y));
        acc[4] += (bf_lo(v0.z) + bf_lo(v1.z)) + (bf_lo(v2.z) + bf_lo(v3.z));
        acc[5] += (bf_hi(v0.z) + bf_hi(v1.z)) + (bf_hi(v2.z) + bf_hi(v3.z));
        acc[6] += (bf_lo(v0.w) + bf_lo(v1.w)) + (bf_lo(v2.w) + bf_lo(v3.w));
        acc[7] += (bf_hi(v0.w) + bf_hi(v1.w)) + (bf_hi(v2.w) + bf_hi(v3.w));
    }
    for (; e < s1; ++e) {
        uint4 v0 = *(const uint4*)(pc + (size_t)csr_src[e] * 128);
        acc[0] += bf_lo(v0.x); acc[1] += bf_hi(v0.x);
        acc[2] += bf_lo(v0.y); acc[3] += bf_hi(v0.y);
        acc[4] += bf_lo(v0.z); acc[5] += bf_hi(v0.z);
        acc[6] += bf_lo(v0.w); acc[7] += bf_hi(v0.w);
    }
    float inv = 1.0f / (float)max(s1 - s0, 1);
    uint4 qv = *(const uint4*)(q + (size_t)n * 128 + lane * 8);
    float hv[8];
    hv[0] = fmaxf(fmaf(acc[0], inv, bf_lo(qv.x)), 0.f);
    hv[1] = fmaxf(fmaf(acc[1], inv, bf_hi(qv.x)), 0.f);
    hv[2] = fmaxf(fmaf(acc[2], inv, bf_lo(qv.y)), 0.f);
    hv[3] = fmaxf(fmaf(acc[3], inv, bf_hi(qv.y)), 0.f);
    hv[4] = fmaxf(fmaf(acc[4], inv, bf_lo(qv.z)), 0.f);
    hv[5] = fmaxf(fmaf(acc[5], inv, bf_hi(qv.z)), 0.f);
    hv[6] = fmaxf(fmaf(acc[6], inv, bf_lo(qv.w)), 0.f);
    hv[7] = fmaxf(fmaf(acc[7], inv, bf_hi(qv.w)), 0.f);
    uint4 o;
    o.x = packbf(hv[0], hv[1]); o.y = packbf(hv[2], hv[3]);
    o.z = packbf(hv[4], hv[5]); o.w = packbf(hv[6], hv[7]);
    *(uint4*)(h + (size_t)n * 128 + lane * 8) = o;
}

// layer 2: out[n] = mean(g[src]) + r[n]; g,r bf16; out f32; 64 ch.
__global__ __launch_bounds__(256) void agg2_kernel(const unsigned short* __restrict__ g,
                                                   const unsigned short* __restrict__ r,
                                                   const int* __restrict__ row_start,
                                                   const int* __restrict__ csr_src,
                                                   float* __restrict__ out, int N) {
    int tid = threadIdx.x;
    int n = blockIdx.x * 16 + (tid >> 4);
    int lane = tid & 15;
    if (n >= N) return;
    int s0 = row_start[n], s1 = row_start[n + 1];
    float acc[4] = {};
    const unsigned short* gc = g + lane * 4;
    int e = s0;
    for (; e + 3 < s1; e += 4) {
        uint2 v0 = *(const uint2*)(gc + (size_t)csr_src[e]     * 64);
        uint2 v1 = *(const uint2*)(gc + (size_t)csr_src[e + 1] * 64);
        uint2 v2 = *(const uint2*)(gc + (size_t)csr_src[e + 2] * 64);
        uint2 v3 = *(const uint2*)(gc + (size_t)csr_src[e + 3] * 64);
        acc[0] += (bf_lo(v0.x) + bf_lo(v1.x)) + (bf_lo(v2.x) + bf_lo(v3.x));
        acc[1] += (bf_hi(v0.x) + bf_hi(v1.x)) + (bf_hi(v2.x) + bf_hi(v3.x));
        acc[2] += (bf_lo(v0.y) + bf_lo(v1.y)) + (bf_lo(v2.y) + bf_lo(v3.y));
        acc[3] += (bf_hi(v0.y) + bf_hi(v1.y)) + (bf_hi(v2.y) + bf_hi(v3.y));
    }
    for (; e < s1; ++e) {
        uint2 v0 = *(const uint2*)(gc + (size_t)csr_src[e] * 64);
        acc[0] += bf_lo(v0.x); acc[1] += bf_hi(v0.x);
        acc[2] += bf_lo(v0.y); acc[3] += bf_hi(v0.y);
    }
    float inv = 1.0f / (float)max(s1 - s0, 1);
    uint2 rv = *(const uint2*)(r + (size_t)n * 64 + lane * 4);
    float4 o;
    o.x = fmaf(acc[0], inv, bf_lo(rv.x));
    o.y = fmaf(acc[1], inv, bf_hi(rv.x));
    o.z = fmaf(acc[2], inv, bf_lo(rv.y));
    o.w = fmaf(acc[3], inv, bf_hi(rv.y));
    *(float4*)(out + (size_t)n * 64 + lane * 4) = o;
}

// ---------------------------------------------------------------------------

extern "C" void kernel_launch(void* const* d_in, const int* in_sizes, int n_in,
                              void* d_out, int out_size, void* d_ws, size_t ws_size,
                              hipStream_t stream) {
    const float* x    = (const float*)d_in[0];
    const int*   ei   = (const int*)d_in[1];
    const float* W1_l = (const float*)d_in[2];
    const float* b1   = (const float*)d_in[3];
    const float* W1_r = (const float*)d_in[4];
    const float* W2_l = (const float*)d_in[5];
    const float* b2   = (const float*)d_in[6];
    const float* W2_r = (const float*)d_in[7];

    const int N = in_sizes[0] / 128;   // 50000
    const int E = in_sizes[1] / 2;     // 800000
    const int* e_src = ei;
    const int* e_dst = ei + E;

    // ---- workspace layout ----
    char* ws = (char*)d_ws;
    auto align256 = [](size_t v) { return (v + 255) & ~(size_t)255; };
    size_t off = 0;
    int* row_start = (int*)(ws + off); off += align256((size_t)(N + 1) * 4);
    int* bsum      = (int*)(ws + off); off += align256(1024);
    int* hist      = (int*)(ws + off); off += align256((size_t)NRANGE * NSTRIPE * PACKED_W * 4);
    int* cur       = (int*)(ws + off); off += align256((size_t)NRANGE * NSTRIPE * RANGE_W * 4);
    int* csr_src   = (int*)(ws + off); off += align256((size_t)E * 4);
    unsigned short* h_bf  = (unsigned short*)(ws + off); off += align256((size_t)N * 128 * 2);
    unsigned short* pg_bf = (unsigned short*)(ws + off); off += align256((size_t)N * 128 * 2);
    unsigned short* qr_bf = (unsigned short*)(ws + off); off += align256((size_t)N * 128 * 2);
    unsigned short* wt1l  = (unsigned short*)(ws + off); off += align256(128 * 128 * 2);
    unsigned short* wt1r  = (unsigned short*)(ws + off); off += align256(128 * 128 * 2);
    unsigned short* wt2l  = (unsigned short*)(ws + off); off += align256(128 * 64 * 2);
    unsigned short* wt2r  = (unsigned short*)(ws + off); off += align256(128 * 64 * 2);
    float* out = (float*)d_out;

    const int nb = (N + 255) / 256;
    const int nGemmWg = (N + 63) / 64;
    const int nWtWg = (16384 + 8192 + 255) / 256;   // 96

    // ---- D1: histogram + weight prep (fused, hist first) ----
    hist_wt_kernel<<<NHIST + nWtWg, 256, 0, stream>>>(
        e_dst, hist, E, N, W1_l, W1_r, W2_l, W2_r, wt1l, wt1r, wt2l, wt2r);
    // ---- D2/D3: CSR scan (no global atomics) ----
    scan16_kernel<<<nb, 256, 0, stream>>>(hist, row_start, bsum, N);
    add_off_base_kernel<<<nb, 256, 0, stream>>>(row_start, bsum, hist, cur, N, E);
    // ---- D4: scatter + GEMM-1 (p, q+b1) fused, scatter first ----
    scatter_gemm1_kernel<<<NHIST + nGemmWg, 256, 0, stream>>>(
        e_src, e_dst, cur, csr_src, E, N,
        x, wt1l, wt1r, b1, pg_bf, qr_bf, N);
    // ---- layer 1 aggregate ----
    agg1_kernel<<<(N + 15) / 16, 256, 0, stream>>>(pg_bf, qr_bf, row_start,
                                                   csr_src, h_bf, N);
    // ---- layer 2 ----
    mfma_dual_gemm2<<<(N + 63) / 64, 256, 0, stream>>>(h_bf, wt2l, wt2r, b2,
                                                       pg_bf, qr_bf, N);
    agg2_kernel<<<(N + 15) / 16, 256, 0, stream>>>(pg_bf, qr_bf, row_start,
                                                   csr_src, out, N);
}

// Round 12
// 140.610 us; speedup vs baseline: 1.1877x; 1.0506x over previous
//
#include <hip/hip_runtime.h>
#include <hip/hip_bf16.h>

// ---------------------------------------------------------------------------
// GraphSAGE 2-layer forward.
//   h   = relu( mean_agg(x) @ W1_l + b1 + x @ W1_r )
//   out =       mean_agg(h) @ W2_l + b2 + h @ W2_r
// agg(x)@W == agg(x@W): transform-then-aggregate. Biases folded into the
// GEMM epilogue of the root term (q = x@W1_r + b1, r = h@W2_r + b2).
// bf16 MFMA GEMMs; bf16 gather buffers (p,g) and addends (q,r); fp32 out.
// CSR build with ZERO global atomics (NSTRIPE=32):
//   D1 hist+wt (512 thr): packed 2xushort LDS hist, hist blocks first.
//   D2 scan16: cnt[n] = sum_j hist, block scan -> row_start.
//   D3 add_off_base: global prefix; absolute cursors (unpacked) to cur.
//   D4 scatter+GEMM1 (512 thr): scatter blocks first (cursors->LDS,
//      LDS-atomic pos, plain stores, blockIdx&7==range -> XCD-local);
//      GEMM-1 blocks (128 rows, 8 waves) backfill.
// Aggregation: 4 nodes/wave, 16 lanes/node, 16B/lane, 8-deep gather unroll.
// ---------------------------------------------------------------------------

typedef __attribute__((ext_vector_type(8))) short bf16x8;
typedef __attribute__((ext_vector_type(4))) float f32x4;

static __device__ __forceinline__ float bf_lo(unsigned u) {
    u <<= 16; return __builtin_bit_cast(float, u);
}
static __device__ __forceinline__ float bf_hi(unsigned u) {
    u &= 0xffff0000u; return __builtin_bit_cast(float, u);
}
static __device__ __forceinline__ unsigned short f2bf(float f) {
    __hip_bfloat16 b = __float2bfloat16(f);
    return __builtin_bit_cast(unsigned short, b);
}
static __device__ __forceinline__ unsigned packbf(float lo, float hi) {
    return (unsigned)f2bf(lo) | ((unsigned)f2bf(hi) << 16);
}

#define NRANGE   8
#define RANGE_W  6250      // N == 8*6250 exactly
#define PACKED_W 3125      // RANGE_W/2, two ushort counts per int
#define NSTRIPE  32
#define NHIST    (NRANGE * NSTRIPE)   // 256

static __device__ __forceinline__ int stripe_len(int E) {
    return ((E / NSTRIPE) + 3) & ~3;  // multiple of 4 for int4 alignment
}

// ---------------- MFMA dual GEMM body ----------------
// A[M][128] row-major (fp32 if A_F32 else bf16); WTl/WTr[NC][128] bf16 (=W^T).
// Pl = A@Wl (bf16), Qr = A@Wr + bias (bf16). One wave = 16 output rows;
// WPB waves per block (block covers WPB*16 rows).
// mfma_f32_16x16x32_bf16: A lane l -> row l&15, k=(l>>4)*8+j; B lane l ->
// col l&15, same k; D: col=lane&15, row=(lane>>4)*4+reg.

template <int NC, bool A_F32, int WPB>
static __device__ __forceinline__ void gemm_body(
    int bid, int tid, const void* __restrict__ Av,
    const unsigned short* __restrict__ WTl,
    const unsigned short* __restrict__ WTr,
    const float* __restrict__ bias,
    unsigned short* __restrict__ Pl,
    unsigned short* __restrict__ Qr, int M) {
    const int wave = tid >> 6;
    const int lane = tid & 63;
    const int m0 = bid * (WPB * 16) + wave * 16;
    const int lr = lane & 15;
    const int lk = lane >> 4;

    int arow = m0 + lr;
    if (arow >= M) arow = M - 1;

    bf16x8 af[4];
    if (A_F32) {
        const float* Ab = (const float*)Av + (size_t)arow * 128 + lk * 8;
#pragma unroll
        for (int s = 0; s < 4; ++s) {
            float4 v0 = *(const float4*)(Ab + s * 32);
            float4 v1 = *(const float4*)(Ab + s * 32 + 4);
            unsigned short t[8] = {f2bf(v0.x), f2bf(v0.y), f2bf(v0.z), f2bf(v0.w),
                                   f2bf(v1.x), f2bf(v1.y), f2bf(v1.z), f2bf(v1.w)};
            af[s] = *(const bf16x8*)t;
        }
    } else {
        const unsigned short* Ab = (const unsigned short*)Av + (size_t)arow * 128 + lk * 8;
#pragma unroll
        for (int s = 0; s < 4; ++s) af[s] = *(const bf16x8*)(Ab + s * 32);
    }

#pragma unroll
    for (int ct = 0; ct < NC / 16; ++ct) {
        const unsigned short* Bl = WTl + (size_t)(ct * 16 + lr) * 128 + lk * 8;
        const unsigned short* Br = WTr + (size_t)(ct * 16 + lr) * 128 + lk * 8;
        f32x4 accL = {0.f, 0.f, 0.f, 0.f};
        f32x4 accR = {0.f, 0.f, 0.f, 0.f};
#pragma unroll
        for (int s = 0; s < 4; ++s) {
            bf16x8 bl = *(const bf16x8*)(Bl + s * 32);
            bf16x8 br = *(const bf16x8*)(Br + s * 32);
            accL = __builtin_amdgcn_mfma_f32_16x16x32_bf16(af[s], bl, accL, 0, 0, 0);
            accR = __builtin_amdgcn_mfma_f32_16x16x32_bf16(af[s], br, accR, 0, 0, 0);
        }
        float bcol = bias[ct * 16 + lr];
#pragma unroll
        for (int r = 0; r < 4; ++r) {
            int gr = m0 + lk * 4 + r;
            if (gr < M) {
                Pl[(size_t)gr * NC + ct * 16 + lr] = f2bf(accL[r]);
                Qr[(size_t)gr * NC + ct * 16 + lr] = f2bf(accR[r] + bcol);
            }
        }
    }
}

// ---------------- D1: hist (blocks 0..NHIST) + weight prep (backfill) ------
// 512 threads; 2x-unrolled edge loop (4 int4 loads in flight per thread).

__global__ __launch_bounds__(512) void hist_wt_kernel(
    const int* __restrict__ dst, int* __restrict__ hist, int E, int N,
    const float* __restrict__ W1l, const float* __restrict__ W1r,
    const float* __restrict__ W2l, const float* __restrict__ W2r,
    unsigned short* __restrict__ T1l, unsigned short* __restrict__ T1r,
    unsigned short* __restrict__ T2l, unsigned short* __restrict__ T2r) {
    __shared__ int lhist[PACKED_W];
    const int tid = threadIdx.x;
    if ((int)blockIdx.x >= NHIST) {
        int i = (blockIdx.x - NHIST) * 512 + tid;
        if (i < 16384) {
            int k = i >> 7, n = i & 127;
            T1l[n * 128 + k] = f2bf(W1l[i]);
            T1r[n * 128 + k] = f2bf(W1r[i]);
        } else if (i < 16384 + 8192) {
            int m = i - 16384;
            int k = m >> 6, n = m & 63;
            T2l[n * 128 + k] = f2bf(W2l[m]);
            T2r[n * 128 + k] = f2bf(W2r[m]);
        }
        return;
    }
    const int b = blockIdx.x;
    const int r = b & (NRANGE - 1);
    const int j = b >> 3;
    const int lo = r * RANGE_W;
    const int w = min(N - lo, RANGE_W);
    for (int i = tid; i < PACKED_W; i += 512) lhist[i] = 0;
    __syncthreads();
    const int stripe = stripe_len(E);
    const int s0 = j * stripe;
    const int s1 = min(E, s0 + stripe);
    for (int e = s0 + tid * 4; e < s1; e += 4096) {
        int4 dA = *(const int4*)(dst + e);
        int eB = e + 2048;
        bool hb = eB < s1;
        int4 dB = hb ? *(const int4*)(dst + eB) : dA;
        int a0 = dA.x - lo, a1 = dA.y - lo, a2 = dA.z - lo, a3 = dA.w - lo;
        if ((unsigned)a0 < (unsigned)w) atomicAdd(&lhist[a0 >> 1], 1u << ((a0 & 1) * 16));
        if ((unsigned)a1 < (unsigned)w) atomicAdd(&lhist[a1 >> 1], 1u << ((a1 & 1) * 16));
        if ((unsigned)a2 < (unsigned)w) atomicAdd(&lhist[a2 >> 1], 1u << ((a2 & 1) * 16));
        if ((unsigned)a3 < (unsigned)w) atomicAdd(&lhist[a3 >> 1], 1u << ((a3 & 1) * 16));
        if (hb) {
            int b0 = dB.x - lo, b1_ = dB.y - lo, b2_ = dB.z - lo, b3 = dB.w - lo;
            if ((unsigned)b0 < (unsigned)w) atomicAdd(&lhist[b0 >> 1], 1u << ((b0 & 1) * 16));
            if ((unsigned)b1_ < (unsigned)w) atomicAdd(&lhist[b1_ >> 1], 1u << ((b1_ & 1) * 16));
            if ((unsigned)b2_ < (unsigned)w) atomicAdd(&lhist[b2_ >> 1], 1u << ((b2_ & 1) * 16));
            if ((unsigned)b3 < (unsigned)w) atomicAdd(&lhist[b3 >> 1], 1u << ((b3 & 1) * 16));
        }
    }
    __syncthreads();
    int* gh = hist + ((size_t)r * NSTRIPE + j) * PACKED_W;
    for (int i = tid; i < PACKED_W; i += 512) gh[i] = lhist[i];
}

// ---------------- D2: scan ----------------

__global__ __launch_bounds__(256) void scan16_kernel(const int* __restrict__ hist,
                                                     int* __restrict__ row_start,
                                                     int* __restrict__ bsum, int N) {
    __shared__ int lds[256];
    int i = blockIdx.x * 256 + threadIdx.x;
    int v = 0;
    if (i < N) {
        int r = i / RANGE_W, loc = i - r * RANGE_W;
        const int* hp = hist + (size_t)r * NSTRIPE * PACKED_W + (loc >> 1);
        int sh = (loc & 1) * 16;
#pragma unroll 8
        for (int j = 0; j < NSTRIPE; ++j) v += (hp[j * PACKED_W] >> sh) & 0xffff;
    }
    lds[threadIdx.x] = v;
    __syncthreads();
    for (int off = 1; off < 256; off <<= 1) {
        int t = (threadIdx.x >= off) ? lds[threadIdx.x - off] : 0;
        __syncthreads();
        lds[threadIdx.x] += t;
        __syncthreads();
    }
    if (i < N) row_start[i] = lds[threadIdx.x] - v;
    if (threadIdx.x == 255) bsum[blockIdx.x] = lds[255];
}

// ---------------- D3: global prefix + absolute cursors ----------------

__global__ __launch_bounds__(256) void add_off_base_kernel(int* __restrict__ row_start,
                                                           const int* __restrict__ bsum,
                                                           const int* __restrict__ hist,
                                                           int* __restrict__ cur,
                                                           int N, int E) {
    __shared__ int lds[256];
    int b = blockIdx.x;
    lds[threadIdx.x] = (threadIdx.x < b) ? bsum[threadIdx.x] : 0;
    __syncthreads();
    for (int off = 128; off > 0; off >>= 1) {
        if (threadIdx.x < off) lds[threadIdx.x] += lds[threadIdx.x + off];
        __syncthreads();
    }
    int prefix = lds[0];
    int i = b * 256 + threadIdx.x;
    if (i < N) {
        int s = row_start[i] + prefix;
        row_start[i] = s;
        int r = i / RANGE_W, loc = i - r * RANGE_W;
        const int* hp = hist + (size_t)r * NSTRIPE * PACKED_W + (loc >> 1);
        int* cp = cur + (size_t)r * NSTRIPE * RANGE_W + loc;
        int sh = (loc & 1) * 16;
#pragma unroll 8
        for (int j = 0; j < NSTRIPE; ++j) {
            int h = (hp[j * PACKED_W] >> sh) & 0xffff;
            cp[j * RANGE_W] = s;
            s += h;
        }
    }
    if (b == 0 && threadIdx.x == 0) row_start[N] = E;
}

// ---------------- D4: scatter (blocks 0..NHIST) + GEMM-1 (backfill) --------
// 512 threads; scatter 2x-unrolled (4 int4 loads issued before LDS ops).

__global__ __launch_bounds__(512) void scatter_gemm1_kernel(
    const int* __restrict__ src, const int* __restrict__ dst,
    const int* __restrict__ cur, int* __restrict__ csr_src, int E, int N,
    const float* __restrict__ x,
    const unsigned short* __restrict__ wt1l,
    const unsigned short* __restrict__ wt1r,
    const float* __restrict__ b1,
    unsigned short* __restrict__ Pl,
    unsigned short* __restrict__ Qr, int M) {
    __shared__ int lcur[RANGE_W];
    const int tid = threadIdx.x;
    if ((int)blockIdx.x >= NHIST) {
        gemm_body<128, true, 8>(blockIdx.x - NHIST, tid, x, wt1l, wt1r, b1, Pl, Qr, M);
        return;
    }
    const int b = blockIdx.x;
    const int r = b & (NRANGE - 1);
    const int j = b >> 3;
    const int lo = r * RANGE_W;
    const int w = min(N - lo, RANGE_W);
    const int* gb = cur + ((size_t)r * NSTRIPE + j) * RANGE_W;
    for (int i = tid; i < w; i += 512) lcur[i] = gb[i];
    __syncthreads();
    const int stripe = stripe_len(E);
    const int s0 = j * stripe;
    const int s1 = min(E, s0 + stripe);
    for (int e = s0 + tid * 4; e < s1; e += 4096) {
        int4 dA = *(const int4*)(dst + e);
        int4 vA = *(const int4*)(src + e);
        int eB = e + 2048;
        bool hb = eB < s1;
        int4 dB = hb ? *(const int4*)(dst + eB) : dA;
        int4 vB = hb ? *(const int4*)(src + eB) : vA;
        int a0 = dA.x - lo, a1 = dA.y - lo, a2 = dA.z - lo, a3 = dA.w - lo;
        if ((unsigned)a0 < (unsigned)w) { int p = atomicAdd(&lcur[a0], 1); csr_src[p] = vA.x; }
        if ((unsigned)a1 < (unsigned)w) { int p = atomicAdd(&lcur[a1], 1); csr_src[p] = vA.y; }
        if ((unsigned)a2 < (unsigned)w) { int p = atomicAdd(&lcur[a2], 1); csr_src[p] = vA.z; }
        if ((unsigned)a3 < (unsigned)w) { int p = atomicAdd(&lcur[a3], 1); csr_src[p] = vA.w; }
        if (hb) {
            int b0 = dB.x - lo, b1_ = dB.y - lo, b2_ = dB.z - lo, b3 = dB.w - lo;
            if ((unsigned)b0 < (unsigned)w) { int p = atomicAdd(&lcur[b0], 1); csr_src[p] = vB.x; }
            if ((unsigned)b1_ < (unsigned)w) { int p = atomicAdd(&lcur[b1_], 1); csr_src[p] = vB.y; }
            if ((unsigned)b2_ < (unsigned)w) { int p = atomicAdd(&lcur[b2_], 1); csr_src[p] = vB.z; }
            if ((unsigned)b3 < (unsigned)w) { int p = atomicAdd(&lcur[b3], 1); csr_src[p] = vB.w; }
        }
    }
}

__global__ __launch_bounds__(256) void mfma_dual_gemm2(
    const unsigned short* __restrict__ A,
    const unsigned short* __restrict__ WTl,
    const unsigned short* __restrict__ WTr,
    const float* __restrict__ b2,
    unsigned short* __restrict__ Pl,
    unsigned short* __restrict__ Qr, int M) {
    gemm_body<64, false, 4>(blockIdx.x, threadIdx.x, A, WTl, WTr, b2, Pl, Qr, M);
}

// ---------------- aggregation ----------------
// layer 1: h[n] = relu( mean(p[src]) + q[n] ); p,q,h bf16; 128 ch.
// 16 nodes/block; 4 nodes/wave, 16 lanes/node, 8 ch (16B) per lane; 8-deep.
__global__ __launch_bounds__(256) void agg1_kernel(const unsigned short* __restrict__ p,
                                                   const unsigned short* __restrict__ q,
                                                   const int* __restrict__ row_start,
                                                   const int* __restrict__ csr_src,
                                                   unsigned short* __restrict__ h, int N) {
    int tid = threadIdx.x;
    int n = blockIdx.x * 16 + (tid >> 4);
    int lane = tid & 15;
    if (n >= N) return;
    int s0 = row_start[n], s1 = row_start[n + 1];
    float acc[8] = {};
    const unsigned short* pc = p + lane * 8;
    int e = s0;
    for (; e + 7 < s1; e += 8) {
        uint4 v0 = *(const uint4*)(pc + (size_t)csr_src[e]     * 128);
        uint4 v1 = *(const uint4*)(pc + (size_t)csr_src[e + 1] * 128);
        uint4 v2 = *(const uint4*)(pc + (size_t)csr_src[e + 2] * 128);
        uint4 v3 = *(const uint4*)(pc + (size_t)csr_src[e + 3] * 128);
        uint4 v4 = *(const uint4*)(pc + (size_t)csr_src[e + 4] * 128);
        uint4 v5 = *(const uint4*)(pc + (size_t)csr_src[e + 5] * 128);
        uint4 v6 = *(const uint4*)(pc + (size_t)csr_src[e + 6] * 128);
        uint4 v7 = *(const uint4*)(pc + (size_t)csr_src[e + 7] * 128);
        acc[0] += ((bf_lo(v0.x) + bf_lo(v1.x)) + (bf_lo(v2.x) + bf_lo(v3.x)))
                + ((bf_lo(v4.x) + bf_lo(v5.x)) + (bf_lo(v6.x) + bf_lo(v7.x)));
        acc[1] += ((bf_hi(v0.x) + bf_hi(v1.x)) + (bf_hi(v2.x) + bf_hi(v3.x)))
                + ((bf_hi(v4.x) + bf_hi(v5.x)) + (bf_hi(v6.x) + bf_hi(v7.x)));
        acc[2] += ((bf_lo(v0.y) + bf_lo(v1.y)) + (bf_lo(v2.y) + bf_lo(v3.y)))
                + ((bf_lo(v4.y) + bf_lo(v5.y)) + (bf_lo(v6.y) + bf_lo(v7.y)));
        acc[3] += ((bf_hi(v0.y) + bf_hi(v1.y)) + (bf_hi(v2.y) + bf_hi(v3.y)))
                + ((bf_hi(v4.y) + bf_hi(v5.y)) + (bf_hi(v6.y) + bf_hi(v7.y)));
        acc[4] += ((bf_lo(v0.z) + bf_lo(v1.z)) + (bf_lo(v2.z) + bf_lo(v3.z)))
                + ((bf_lo(v4.z) + bf_lo(v5.z)) + (bf_lo(v6.z) + bf_lo(v7.z)));
        acc[5] += ((bf_hi(v0.z) + bf_hi(v1.z)) + (bf_hi(v2.z) + bf_hi(v3.z)))
                + ((bf_hi(v4.z) + bf_hi(v5.z)) + (bf_hi(v6.z) + bf_hi(v7.z)));
        acc[6] += ((bf_lo(v0.w) + bf_lo(v1.w)) + (bf_lo(v2.w) + bf_lo(v3.w)))
                + ((bf_lo(v4.w) + bf_lo(v5.w)) + (bf_lo(v6.w) + bf_lo(v7.w)));
        acc[7] += ((bf_hi(v0.w) + bf_hi(v1.w)) + (bf_hi(v2.w) + bf_hi(v3.w)))
                + ((bf_hi(v4.w) + bf_hi(v5.w)) + (bf_hi(v6.w) + bf_hi(v7.w)));
    }
    for (; e + 3 < s1; e += 4) {
        uint4 v0 = *(const uint4*)(pc + (size_t)csr_src[e]     * 128);
        uint4 v1 = *(const uint4*)(pc + (size_t)csr_src[e + 1] * 128);
        uint4 v2 = *(const uint4*)(pc + (size_t)csr_src[e + 2] * 128);
        uint4 v3 = *(const uint4*)(pc + (size_t)csr_src[e + 3] * 128);
        acc[0] += (bf_lo(v0.x) + bf_lo(v1.x)) + (bf_lo(v2.x) + bf_lo(v3.x));
        acc[1] += (bf_hi(v0.x) + bf_hi(v1.x)) + (bf_hi(v2.x) + bf_hi(v3.x));
        acc[2] += (bf_lo(v0.y) + bf_lo(v1.y)) + (bf_lo(v2.y) + bf_lo(v3.y));
        acc[3] += (bf_hi(v0.y) + bf_hi(v1.y)) + (bf_hi(v2.y) + bf_hi(v3.y));
        acc[4] += (bf_lo(v0.z) + bf_lo(v1.z)) + (bf_lo(v2.z) + bf_lo(v3.z));
        acc[5] += (bf_hi(v0.z) + bf_hi(v1.z)) + (bf_hi(v2.z) + bf_hi(v3.z));
        acc[6] += (bf_lo(v0.w) + bf_lo(v1.w)) + (bf_lo(v2.w) + bf_lo(v3.w));
        acc[7] += (bf_hi(v0.w) + bf_hi(v1.w)) + (bf_hi(v2.w) + bf_hi(v3.w));
    }
    for (; e < s1; ++e) {
        uint4 v0 = *(const uint4*)(pc + (size_t)csr_src[e] * 128);
        acc[0] += bf_lo(v0.x); acc[1] += bf_hi(v0.x);
        acc[2] += bf_lo(v0.y); acc[3] += bf_hi(v0.y);
        acc[4] += bf_lo(v0.z); acc[5] += bf_hi(v0.z);
        acc[6] += bf_lo(v0.w); acc[7] += bf_hi(v0.w);
    }
    float inv = 1.0f / (float)max(s1 - s0, 1);
    uint4 qv = *(const uint4*)(q + (size_t)n * 128 + lane * 8);
    float hv[8];
    hv[0] = fmaxf(fmaf(acc[0], inv, bf_lo(qv.x)), 0.f);
    hv[1] = fmaxf(fmaf(acc[1], inv, bf_hi(qv.x)), 0.f);
    hv[2] = fmaxf(fmaf(acc[2], inv, bf_lo(qv.y)), 0.f);
    hv[3] = fmaxf(fmaf(acc[3], inv, bf_hi(qv.y)), 0.f);
    hv[4] = fmaxf(fmaf(acc[4], inv, bf_lo(qv.z)), 0.f);
    hv[5] = fmaxf(fmaf(acc[5], inv, bf_hi(qv.z)), 0.f);
    hv[6] = fmaxf(fmaf(acc[6], inv, bf_lo(qv.w)), 0.f);
    hv[7] = fmaxf(fmaf(acc[7], inv, bf_hi(qv.w)), 0.f);
    uint4 o;
    o.x = packbf(hv[0], hv[1]); o.y = packbf(hv[2], hv[3]);
    o.z = packbf(hv[4], hv[5]); o.w = packbf(hv[6], hv[7]);
    *(uint4*)(h + (size_t)n * 128 + lane * 8) = o;
}

// layer 2: out[n] = mean(g[src]) + r[n]; g,r bf16; out f32; 64 ch; 8-deep.
__global__ __launch_bounds__(256) void agg2_kernel(const unsigned short* __restrict__ g,
                                                   const unsigned short* __restrict__ r,
                                                   const int* __restrict__ row_start,
                                                   const int* __restrict__ csr_src,
                                                   float* __restrict__ out, int N) {
    int tid = threadIdx.x;
    int n = blockIdx.x * 16 + (tid >> 4);
    int lane = tid & 15;
    if (n >= N) return;
    int s0 = row_start[n], s1 = row_start[n + 1];
    float acc[4] = {};
    const unsigned short* gc = g + lane * 4;
    int e = s0;
    for (; e + 7 < s1; e += 8) {
        uint2 v0 = *(const uint2*)(gc + (size_t)csr_src[e]     * 64);
        uint2 v1 = *(const uint2*)(gc + (size_t)csr_src[e + 1] * 64);
        uint2 v2 = *(const uint2*)(gc + (size_t)csr_src[e + 2] * 64);
        uint2 v3 = *(const uint2*)(gc + (size_t)csr_src[e + 3] * 64);
        uint2 v4 = *(const uint2*)(gc + (size_t)csr_src[e + 4] * 64);
        uint2 v5 = *(const uint2*)(gc + (size_t)csr_src[e + 5] * 64);
        uint2 v6 = *(const uint2*)(gc + (size_t)csr_src[e + 6] * 64);
        uint2 v7 = *(const uint2*)(gc + (size_t)csr_src[e + 7] * 64);
        acc[0] += ((bf_lo(v0.x) + bf_lo(v1.x)) + (bf_lo(v2.x) + bf_lo(v3.x)))
                + ((bf_lo(v4.x) + bf_lo(v5.x)) + (bf_lo(v6.x) + bf_lo(v7.x)));
        acc[1] += ((bf_hi(v0.x) + bf_hi(v1.x)) + (bf_hi(v2.x) + bf_hi(v3.x)))
                + ((bf_hi(v4.x) + bf_hi(v5.x)) + (bf_hi(v6.x) + bf_hi(v7.x)));
        acc[2] += ((bf_lo(v0.y) + bf_lo(v1.y)) + (bf_lo(v2.y) + bf_lo(v3.y)))
                + ((bf_lo(v4.y) + bf_lo(v5.y)) + (bf_lo(v6.y) + bf_lo(v7.y)));
        acc[3] += ((bf_hi(v0.y) + bf_hi(v1.y)) + (bf_hi(v2.y) + bf_hi(v3.y)))
                + ((bf_hi(v4.y) + bf_hi(v5.y)) + (bf_hi(v6.y) + bf_hi(v7.y)));
    }
    for (; e + 3 < s1; e += 4) {
        uint2 v0 = *(const uint2*)(gc + (size_t)csr_src[e]     * 64);
        uint2 v1 = *(const uint2*)(gc + (size_t)csr_src[e + 1] * 64);
        uint2 v2 = *(const uint2*)(gc + (size_t)csr_src[e + 2] * 64);
        uint2 v3 = *(const uint2*)(gc + (size_t)csr_src[e + 3] * 64);
        acc[0] += (bf_lo(v0.x) + bf_lo(v1.x)) + (bf_lo(v2.x) + bf_lo(v3.x));
        acc[1] += (bf_hi(v0.x) + bf_hi(v1.x)) + (bf_hi(v2.x) + bf_hi(v3.x));
        acc[2] += (bf_lo(v0.y) + bf_lo(v1.y)) + (bf_lo(v2.y) + bf_lo(v3.y));
        acc[3] += (bf_hi(v0.y) + bf_hi(v1.y)) + (bf_hi(v2.y) + bf_hi(v3.y));
    }
    for (; e < s1; ++e) {
        uint2 v0 = *(const uint2*)(gc + (size_t)csr_src[e] * 64);
        acc[0] += bf_lo(v0.x); acc[1] += bf_hi(v0.x);
        acc[2] += bf_lo(v0.y); acc[3] += bf_hi(v0.y);
    }
    float inv = 1.0f / (float)max(s1 - s0, 1);
    uint2 rv = *(const uint2*)(r + (size_t)n * 64 + lane * 4);
    float4 o;
    o.x = fmaf(acc[0], inv, bf_lo(rv.x));
    o.y = fmaf(acc[1], inv, bf_hi(rv.x));
    o.z = fmaf(acc[2], inv, bf_lo(rv.y));
    o.w = fmaf(acc[3], inv, bf_hi(rv.y));
    *(float4*)(out + (size_t)n * 64 + lane * 4) = o;
}

// ---------------------------------------------------------------------------

extern "C" void kernel_launch(void* const* d_in, const int* in_sizes, int n_in,
                              void* d_out, int out_size, void* d_ws, size_t ws_size,
                              hipStream_t stream) {
    const float* x    = (const float*)d_in[0];
    const int*   ei   = (const int*)d_in[1];
    const float* W1_l = (const float*)d_in[2];
    const float* b1   = (const float*)d_in[3];
    const float* W1_r = (const float*)d_in[4];
    const float* W2_l = (const float*)d_in[5];
    const float* b2   = (const float*)d_in[6];
    const float* W2_r = (const float*)d_in[7];

    const int N = in_sizes[0] / 128;   // 50000
    const int E = in_sizes[1] / 2;     // 800000
    const int* e_src = ei;
    const int* e_dst = ei + E;

    // ---- workspace layout ----
    char* ws = (char*)d_ws;
    auto align256 = [](size_t v) { return (v + 255) & ~(size_t)255; };
    size_t off = 0;
    int* row_start = (int*)(ws + off); off += align256((size_t)(N + 1) * 4);
    int* bsum      = (int*)(ws + off); off += align256(1024);
    int* hist      = (int*)(ws + off); off += align256((size_t)NRANGE * NSTRIPE * PACKED_W * 4);
    int* cur       = (int*)(ws + off); off += align256((size_t)NRANGE * NSTRIPE * RANGE_W * 4);
    int* csr_src   = (int*)(ws + off); off += align256((size_t)E * 4);
    unsigned short* h_bf  = (unsigned short*)(ws + off); off += align256((size_t)N * 128 * 2);
    unsigned short* pg_bf = (unsigned short*)(ws + off); off += align256((size_t)N * 128 * 2);
    unsigned short* qr_bf = (unsigned short*)(ws + off); off += align256((size_t)N * 128 * 2);
    unsigned short* wt1l  = (unsigned short*)(ws + off); off += align256(128 * 128 * 2);
    unsigned short* wt1r  = (unsigned short*)(ws + off); off += align256(128 * 128 * 2);
    unsigned short* wt2l  = (unsigned short*)(ws + off); off += align256(128 * 64 * 2);
    unsigned short* wt2r  = (unsigned short*)(ws + off); off += align256(128 * 64 * 2);
    float* out = (float*)d_out;

    const int nb = (N + 255) / 256;
    const int nGemm1Wg = (N + 127) / 128;                 // 391 (128 rows/block)
    const int nWtWg = (16384 + 8192 + 511) / 512;         // 48

    // ---- D1: histogram + weight prep (fused, hist first, 512 thr) ----
    hist_wt_kernel<<<NHIST + nWtWg, 512, 0, stream>>>(
        e_dst, hist, E, N, W1_l, W1_r, W2_l, W2_r, wt1l, wt1r, wt2l, wt2r);
    // ---- D2/D3: CSR scan (no global atomics) ----
    scan16_kernel<<<nb, 256, 0, stream>>>(hist, row_start, bsum, N);
    add_off_base_kernel<<<nb, 256, 0, stream>>>(row_start, bsum, hist, cur, N, E);
    // ---- D4: scatter + GEMM-1 (p, q+b1) fused, scatter first, 512 thr ----
    scatter_gemm1_kernel<<<NHIST + nGemm1Wg, 512, 0, stream>>>(
        e_src, e_dst, cur, csr_src, E, N,
        x, wt1l, wt1r, b1, pg_bf, qr_bf, N);
    // ---- layer 1 aggregate ----
    agg1_kernel<<<(N + 15) / 16, 256, 0, stream>>>(pg_bf, qr_bf, row_start,
                                                   csr_src, h_bf, N);
    // ---- layer 2 ----
    mfma_dual_gemm2<<<(N + 63) / 64, 256, 0, stream>>>(h_bf, wt2l, wt2r, b2,
                                                       pg_bf, qr_bf, N);
    agg2_kernel<<<(N + 15) / 16, 256, 0, stream>>>(pg_bf, qr_bf, row_start,
                                                   csr_src, out, N);
}